// Round 1
// baseline (559.548 us; speedup 1.0000x reference)
//
#include <hip/hip_runtime.h>
#include <stdint.h>

typedef unsigned int u32;
typedef unsigned short u16;
typedef __attribute__((ext_vector_type(8))) __bf16 bf16x8;
typedef __attribute__((ext_vector_type(4))) float f32x4;

#define N_ROWS 32768
#define D_DIM 512
#define K_CB 1024

// ---------------- threefry2x32 (matches jax._src.prng) ----------------
__host__ __device__ inline void tf2x32(u32 k0, u32 k1, u32 x0, u32 x1, u32 &o0, u32 &o1) {
  const u32 ks2 = k0 ^ k1 ^ 0x1BD11BDAu;
#define TFR(r) x0 += x1; x1 = (x1 << (r)) | (x1 >> (32 - (r))); x1 ^= x0;
  x0 += k0; x1 += k1;
  TFR(13) TFR(15) TFR(26) TFR(6)
  x0 += k1; x1 += ks2 + 1u;
  TFR(17) TFR(29) TFR(16) TFR(24)
  x0 += ks2; x1 += k0 + 2u;
  TFR(13) TFR(15) TFR(26) TFR(6)
  x0 += k0; x1 += k1 + 3u;
  TFR(17) TFR(29) TFR(16) TFR(24)
  x0 += k1; x1 += ks2 + 4u;
  TFR(13) TFR(15) TFR(26) TFR(6)
  x0 += ks2; x1 += k0 + 5u;
#undef TFR
  o0 = x0; o1 = x1;
}

// gumbel = -log(-log(uniform(tiny,1))) exactly as jax.random.gumbel
__device__ inline float bits_to_gumbel(u32 bits) {
  float f = __uint_as_float((bits >> 9) | 0x3f800000u) - 1.0f; // [0,1)
  const float tiny = 1.17549435e-38f;
  float u = fmaxf(tiny, f + tiny); // f*(1-tiny)+tiny, (1-tiny)==1 in f32
  return -logf(-logf(u));
}

__device__ inline u16 f32_bf16(float x) { // RNE
  u32 u = __float_as_uint(x);
  u += 0x7fffu + ((u >> 16) & 1u);
  return (u16)(u >> 16);
}
__device__ inline float bf16_f32(u16 h) { return __uint_as_float(((u32)h) << 16); }

// ---------------- prep: normalize codebook, split to bf16 hi/lo ----------------
__global__ void __launch_bounds__(256) prep_codebook(const float* __restrict__ cb,
                                                     u16* __restrict__ cn_hi,
                                                     u16* __restrict__ cn_lo) {
  const int lane = threadIdx.x & 63, wid = threadIdx.x >> 6;
  const int row = blockIdx.x * 4 + wid;
  const float* src = cb + (size_t)row * D_DIM;
  float v[8]; float ss = 0.f;
#pragma unroll
  for (int i = 0; i < 8; ++i) { v[i] = src[lane + 64 * i]; ss = fmaf(v[i], v[i], ss); }
#pragma unroll
  for (int off = 32; off; off >>= 1) ss += __shfl_xor(ss, off);
  const float denom = fmaxf(sqrtf(ss), 1e-8f);
#pragma unroll
  for (int i = 0; i < 8; ++i) {
    const float x = v[i] / denom;
    const u16 h = f32_bf16(x);
    const u16 l = f32_bf16(x - bf16_f32(h));
    cn_hi[(size_t)row * D_DIM + lane + 64 * i] = h;
    cn_lo[(size_t)row * D_DIM + lane + 64 * i] = l;
  }
}

// ---------------- prep: m = 0.5*(state/|state| + adv/|adv|), split hi/lo ----------------
__global__ void __launch_bounds__(256) prep_m(const float* __restrict__ se,
                                              const float* __restrict__ ae,
                                              u16* __restrict__ m_hi,
                                              u16* __restrict__ m_lo) {
  const int lane = threadIdx.x & 63, wid = threadIdx.x >> 6;
  const size_t row = (size_t)blockIdx.x * 4 + wid;
  const float* s = se + row * D_DIM;
  const float* a = ae + row * D_DIM;
  float sv[8], av[8]; float ss = 0.f, sa = 0.f;
#pragma unroll
  for (int i = 0; i < 8; ++i) {
    sv[i] = s[lane + 64 * i]; av[i] = a[lane + 64 * i];
    ss = fmaf(sv[i], sv[i], ss); sa = fmaf(av[i], av[i], sa);
  }
#pragma unroll
  for (int off = 32; off; off >>= 1) { ss += __shfl_xor(ss, off); sa += __shfl_xor(sa, off); }
  const float ds = fmaxf(sqrtf(ss), 1e-8f);
  const float da = fmaxf(sqrtf(sa), 1e-8f);
#pragma unroll
  for (int i = 0; i < 8; ++i) {
    const float m = 0.5f * (sv[i] / ds) + 0.5f * (av[i] / da);
    const u16 h = f32_bf16(m);
    const u16 l = f32_bf16(m - bf16_f32(h));
    m_hi[row * D_DIM + lane + 64 * i] = h;
    m_lo[row * D_DIM + lane + 64 * i] = l;
  }
}

// ---------------- GEMM: sim = m @ cn^T  (bf16x2 split, fp32-accurate) ----------------
// 128x128 tile, BK=64, 256 threads (2x2 waves, each 64x64 = 4x4 frags of 16x16x32)
__global__ void __launch_bounds__(256) gemm_sim(const u16* __restrict__ mA_hi,
                                                const u16* __restrict__ mA_lo,
                                                const u16* __restrict__ cn_hi,
                                                const u16* __restrict__ cn_lo,
                                                float* __restrict__ sim) {
  __shared__ __align__(16) u16 As_hi[128 * 64];
  __shared__ __align__(16) u16 As_lo[128 * 64];
  __shared__ __align__(16) u16 Bs_hi[128 * 64];
  __shared__ __align__(16) u16 Bs_lo[128 * 64];

  const int tid = threadIdx.x;
  const int lane = tid & 63;
  const int wid = tid >> 6;
  const int wr = wid >> 1, wc = wid & 1;
  const int bn = blockIdx.x, bm = blockIdx.y;

  const int fr = lane & 15; // A row / B col / C col
  const int q8 = lane >> 4; // k-group (8 elems) / C row-group (4 rows)

  f32x4 acc[4][4];
#pragma unroll
  for (int i = 0; i < 4; ++i)
#pragma unroll
    for (int j = 0; j < 4; ++j) acc[i][j] = (f32x4){0.f, 0.f, 0.f, 0.f};

  const int o_base = wid * 1024 + lane * 16; // byte offset within 16KB tile (+ i*4096)
  const char* gA_hi = (const char*)mA_hi + (size_t)(bm * 128) * (D_DIM * 2);
  const char* gA_lo = (const char*)mA_lo + (size_t)(bm * 128) * (D_DIM * 2);
  const char* gB_hi = (const char*)cn_hi + (size_t)(bn * 128) * (D_DIM * 2);
  const char* gB_lo = (const char*)cn_lo + (size_t)(bn * 128) * (D_DIM * 2);

  for (int kt = 0; kt < D_DIM / 64; ++kt) {
    const int kbyte = kt * 128;
#pragma unroll
    for (int i = 0; i < 4; ++i) {
      const int o = o_base + i * 4096;
      const int row = o >> 7;     // 128 B per LDS row
      const int cbyt = o & 127;
      const size_t goff = (size_t)row * (D_DIM * 2) + kbyte + cbyt;
      const int loff = wid * 1024 + i * 4096;
      __builtin_amdgcn_global_load_lds((const __attribute__((address_space(1))) void*)(gA_hi + goff),
                                       (__attribute__((address_space(3))) void*)((char*)As_hi + loff), 16, 0, 0);
      __builtin_amdgcn_global_load_lds((const __attribute__((address_space(1))) void*)(gA_lo + goff),
                                       (__attribute__((address_space(3))) void*)((char*)As_lo + loff), 16, 0, 0);
      __builtin_amdgcn_global_load_lds((const __attribute__((address_space(1))) void*)(gB_hi + goff),
                                       (__attribute__((address_space(3))) void*)((char*)Bs_hi + loff), 16, 0, 0);
      __builtin_amdgcn_global_load_lds((const __attribute__((address_space(1))) void*)(gB_lo + goff),
                                       (__attribute__((address_space(3))) void*)((char*)Bs_lo + loff), 16, 0, 0);
    }
    __syncthreads(); // compiler drains vmcnt(0) before barrier -> LDS valid

#pragma unroll
    for (int kk = 0; kk < 2; ++kk) {
      bf16x8 ah[4], al[4], bh[4], bl[4];
      const int co = kk * 32 + q8 * 8;
#pragma unroll
      for (int mi = 0; mi < 4; ++mi) {
        const int r = wr * 64 + mi * 16 + fr;
        ah[mi] = *(const bf16x8*)&As_hi[r * 64 + co];
        al[mi] = *(const bf16x8*)&As_lo[r * 64 + co];
      }
#pragma unroll
      for (int ni = 0; ni < 4; ++ni) {
        const int r = wc * 64 + ni * 16 + fr;
        bh[ni] = *(const bf16x8*)&Bs_hi[r * 64 + co];
        bl[ni] = *(const bf16x8*)&Bs_lo[r * 64 + co];
      }
#pragma unroll
      for (int mi = 0; mi < 4; ++mi)
#pragma unroll
        for (int ni = 0; ni < 4; ++ni) {
          acc[mi][ni] = __builtin_amdgcn_mfma_f32_16x16x32_bf16(ah[mi], bh[ni], acc[mi][ni], 0, 0, 0);
          acc[mi][ni] = __builtin_amdgcn_mfma_f32_16x16x32_bf16(ah[mi], bl[ni], acc[mi][ni], 0, 0, 0);
          acc[mi][ni] = __builtin_amdgcn_mfma_f32_16x16x32_bf16(al[mi], bh[ni], acc[mi][ni], 0, 0, 0);
        }
    }
    __syncthreads();
  }

  // C layout (verified m89/m91): col = lane&15, row = (lane>>4)*4 + reg
  const int row_base = bm * 128 + wr * 64 + q8 * 4;
  const int col_base = bn * 128 + wc * 64 + fr;
#pragma unroll
  for (int mi = 0; mi < 4; ++mi)
#pragma unroll
    for (int ni = 0; ni < 4; ++ni) {
      const int r0 = row_base + mi * 16;
      const int c = col_base + ni * 16;
#pragma unroll
      for (int r = 0; r < 4; ++r)
        sim[(size_t)(r0 + r) * K_CB + c] = acc[mi][ni][r];
    }
}

// ---------------- epilogue: gumbel argmax + softmax + gather (in-place over sim) ----------------
__global__ void __launch_bounds__(256) gumbel_epilogue(float* __restrict__ simw, // in: sim, out: weights_soft
                                                       float* __restrict__ zq,
                                                       float* __restrict__ idxf,
                                                       const float* __restrict__ cb,
                                                       u32 k1a, u32 k1b, u32 k2a, u32 k2b) {
  const int n = blockIdx.x;
  const int tid = threadIdx.x;
  const int lane = tid & 63, wid = tid >> 6;
  float* row = simw + (size_t)n * K_CB;
  const u32 base = (u32)n * K_CB;

  float l1[4], l2[4];
#pragma unroll
  for (int i = 0; i < 4; ++i) {
    const int k = tid + i * 256;
    const float s = row[k];
    u32 a0, a1, b0, b1;
    tf2x32(k1a, k1b, 0u, base + (u32)k, a0, a1); // partitionable: block on (hi=0, lo=flat idx)
    tf2x32(k2a, k2b, 0u, base + (u32)k, b0, b1);
    l1[i] = s + bits_to_gumbel(a0 ^ a1);
    l2[i] = s + bits_to_gumbel(b0 ^ b1);
  }

  // argmax over l1 (first-index tie-break, matching jnp.argmax)
  float bv = l1[0]; int bi = tid;
#pragma unroll
  for (int i = 1; i < 4; ++i) {
    const int k = tid + i * 256;
    if (l1[i] > bv) { bv = l1[i]; bi = k; }
  }
#pragma unroll
  for (int off = 1; off < 64; off <<= 1) {
    const float ov = __shfl_xor(bv, off);
    const int oi = __shfl_xor(bi, off);
    if (ov > bv || (ov == bv && oi < bi)) { bv = ov; bi = oi; }
  }
  // max over l2
  float mx = fmaxf(fmaxf(l2[0], l2[1]), fmaxf(l2[2], l2[3]));
#pragma unroll
  for (int off = 1; off < 64; off <<= 1) mx = fmaxf(mx, __shfl_xor(mx, off));

  __shared__ float svv[4]; __shared__ int sii[4];
  __shared__ float smx[4]; __shared__ float ssm[4];
  if (lane == 0) { svv[wid] = bv; sii[wid] = bi; smx[wid] = mx; }
  __syncthreads();
  bv = svv[0]; bi = sii[0];
#pragma unroll
  for (int w = 1; w < 4; ++w)
    if (svv[w] > bv || (svv[w] == bv && sii[w] < bi)) { bv = svv[w]; bi = sii[w]; }
  mx = fmaxf(fmaxf(smx[0], smx[1]), fmaxf(smx[2], smx[3]));

  float p[4]; float ps = 0.f;
#pragma unroll
  for (int i = 0; i < 4; ++i) { p[i] = expf(l2[i] - mx); ps += p[i]; }
#pragma unroll
  for (int off = 1; off < 64; off <<= 1) ps += __shfl_xor(ps, off);
  if (lane == 0) ssm[wid] = ps;
  __syncthreads();
  const float tot = ssm[0] + ssm[1] + ssm[2] + ssm[3];

#pragma unroll
  for (int i = 0; i < 4; ++i) row[tid + i * 256] = p[i] / tot;

  // z_q = codebook[argmax]  (one-hot @ codebook == gather)
  const float* crow = cb + (size_t)bi * D_DIM;
  for (int j = tid; j < D_DIM; j += 256) zq[(size_t)n * D_DIM + j] = crow[j];
  if (tid == 0) idxf[n] = (float)bi;
}

// ---------------- host ----------------
extern "C" void kernel_launch(void* const* d_in, const int* in_sizes, int n_in,
                              void* d_out, int out_size, void* d_ws, size_t ws_size,
                              hipStream_t stream) {
  const float* state = (const float*)d_in[0];
  const float* adv = (const float*)d_in[1];
  const float* cb = (const float*)d_in[2];

  char* ws = (char*)d_ws;
  u16* m_hi = (u16*)ws;                                 // 32 MB
  u16* m_lo = (u16*)(ws + (size_t)N_ROWS * D_DIM * 2);  // 32 MB
  u16* cn_hi = (u16*)(ws + (size_t)N_ROWS * D_DIM * 4);                          // 1 MB
  u16* cn_lo = (u16*)(ws + (size_t)N_ROWS * D_DIM * 4 + (size_t)K_CB * D_DIM * 2); // 1 MB

  float* zq = (float*)d_out;                       // [N, D]
  float* simw = zq + (size_t)N_ROWS * D_DIM;       // [N, K] sim -> weights_soft (in-place)
  float* idxf = simw + (size_t)N_ROWS * K_CB;      // [N, 1] as float

  // jax.random.key(42) -> (0,42); fold-like split (partitionable default):
  // gk1 = E(0,0), gk2 = E(0,1)
  u32 gk1a, gk1b, gk2a, gk2b;
  tf2x32(0u, 42u, 0u, 0u, gk1a, gk1b);
  tf2x32(0u, 42u, 0u, 1u, gk2a, gk2b);

  hipLaunchKernelGGL(prep_codebook, dim3(K_CB / 4), dim3(256), 0, stream, cb, cn_hi, cn_lo);
  hipLaunchKernelGGL(prep_m, dim3(N_ROWS / 4), dim3(256), 0, stream, state, adv, m_hi, m_lo);
  hipLaunchKernelGGL(gemm_sim, dim3(K_CB / 128, N_ROWS / 128), dim3(256), 0, stream,
                     m_hi, m_lo, cn_hi, cn_lo, simw);
  hipLaunchKernelGGL(gumbel_epilogue, dim3(N_ROWS), dim3(256), 0, stream,
                     simw, zq, idxf, cb, gk1a, gk1b, gk2a, gk2b);
}

// Round 2
// 528.010 us; speedup vs baseline: 1.0597x; 1.0597x over previous
//
#include <hip/hip_runtime.h>
#include <stdint.h>

typedef unsigned int u32;
typedef unsigned short u16;
typedef __attribute__((ext_vector_type(8))) __bf16 bf16x8;
typedef __attribute__((ext_vector_type(4))) float f32x4;

#define N_ROWS 32768
#define D_DIM 512
#define K_CB 1024

// ---------------- threefry2x32 (matches jax._src.prng, partitionable) ----------------
__host__ __device__ inline void tf2x32(u32 k0, u32 k1, u32 x0, u32 x1, u32 &o0, u32 &o1) {
  const u32 ks2 = k0 ^ k1 ^ 0x1BD11BDAu;
#define TFR(r) x0 += x1; x1 = (x1 << (r)) | (x1 >> (32 - (r))); x1 ^= x0;
  x0 += k0; x1 += k1;
  TFR(13) TFR(15) TFR(26) TFR(6)
  x0 += k1; x1 += ks2 + 1u;
  TFR(17) TFR(29) TFR(16) TFR(24)
  x0 += ks2; x1 += k0 + 2u;
  TFR(13) TFR(15) TFR(26) TFR(6)
  x0 += k0; x1 += k1 + 3u;
  TFR(17) TFR(29) TFR(16) TFR(24)
  x0 += k1; x1 += ks2 + 4u;
  TFR(13) TFR(15) TFR(26) TFR(6)
  x0 += ks2; x1 += k0 + 5u;
#undef TFR
  o0 = x0; o1 = x1;
}

// gumbel = -log(-log(max(tiny, f+tiny))) via native v_log_f32:
// -log(u) = -ln2*log2(u); -log(v) = -ln2*log2(v)
__device__ inline float gumbel_fast(u32 bits) {
  const float f = __uint_as_float((bits >> 9) | 0x3f800000u) - 1.0f; // [0,1)
  const float tiny = 1.17549435e-38f;
  const float u = fmaxf(tiny, f + tiny);
  const float NLN2 = -0.69314718055994530942f;
  const float a = __log2f(u);   // <= 0
  const float v = a * NLN2;     // -log(u) in (0, 87.4]
  const float b = __log2f(v);
  return b * NLN2;              // in [-4.48, 16.7] for f32 uniforms
}

__device__ inline u16 f32_bf16(float x) { // RNE
  u32 u = __float_as_uint(x);
  u += 0x7fffu + ((u >> 16) & 1u);
  return (u16)(u >> 16);
}
__device__ inline float bf16_f32(u16 h) { return __uint_as_float(((u32)h) << 16); }

// ---------------- prep: normalize codebook, split to bf16 hi/lo ----------------
__global__ void __launch_bounds__(256) prep_codebook(const float* __restrict__ cb,
                                                     u16* __restrict__ cn_hi,
                                                     u16* __restrict__ cn_lo) {
  const int lane = threadIdx.x & 63, wid = threadIdx.x >> 6;
  const int row = blockIdx.x * 4 + wid;
  const float* src = cb + (size_t)row * D_DIM;
  float v[8]; float ss = 0.f;
#pragma unroll
  for (int i = 0; i < 8; ++i) { v[i] = src[lane + 64 * i]; ss = fmaf(v[i], v[i], ss); }
#pragma unroll
  for (int off = 32; off; off >>= 1) ss += __shfl_xor(ss, off);
  const float denom = fmaxf(sqrtf(ss), 1e-8f);
#pragma unroll
  for (int i = 0; i < 8; ++i) {
    const float x = v[i] / denom;
    const u16 h = f32_bf16(x);
    const u16 l = f32_bf16(x - bf16_f32(h));
    cn_hi[(size_t)row * D_DIM + lane + 64 * i] = h;
    cn_lo[(size_t)row * D_DIM + lane + 64 * i] = l;
  }
}

// ---------------- prep: m = 0.5*(state/|state| + adv/|adv|), split hi/lo ----------------
__global__ void __launch_bounds__(256) prep_m(const float* __restrict__ se,
                                              const float* __restrict__ ae,
                                              u16* __restrict__ m_hi,
                                              u16* __restrict__ m_lo) {
  const int lane = threadIdx.x & 63, wid = threadIdx.x >> 6;
  const size_t row = (size_t)blockIdx.x * 4 + wid;
  const float* s = se + row * D_DIM;
  const float* a = ae + row * D_DIM;
  float sv[8], av[8]; float ss = 0.f, sa = 0.f;
#pragma unroll
  for (int i = 0; i < 8; ++i) {
    sv[i] = s[lane + 64 * i]; av[i] = a[lane + 64 * i];
    ss = fmaf(sv[i], sv[i], ss); sa = fmaf(av[i], av[i], sa);
  }
#pragma unroll
  for (int off = 32; off; off >>= 1) { ss += __shfl_xor(ss, off); sa += __shfl_xor(sa, off); }
  const float ds = fmaxf(sqrtf(ss), 1e-8f);
  const float da = fmaxf(sqrtf(sa), 1e-8f);
#pragma unroll
  for (int i = 0; i < 8; ++i) {
    const float m = 0.5f * (sv[i] / ds) + 0.5f * (av[i] / da);
    const u16 h = f32_bf16(m);
    const u16 l = f32_bf16(m - bf16_f32(h));
    m_hi[row * D_DIM + lane + 64 * i] = h;
    m_lo[row * D_DIM + lane + 64 * i] = l;
  }
}

// ---------------- GEMM: sim = m @ cn^T  (bf16x2 split, 3-term, fp32-accurate) ----------------
// 128x128 tile, BK=64, 256 threads (2x2 waves, each 64x64 = 4x4 frags of 16x16x32)
__global__ void __launch_bounds__(256) gemm_sim(const u16* __restrict__ mA_hi,
                                                const u16* __restrict__ mA_lo,
                                                const u16* __restrict__ cn_hi,
                                                const u16* __restrict__ cn_lo,
                                                float* __restrict__ sim) {
  __shared__ __align__(16) u16 As_hi[128 * 64];
  __shared__ __align__(16) u16 As_lo[128 * 64];
  __shared__ __align__(16) u16 Bs_hi[128 * 64];
  __shared__ __align__(16) u16 Bs_lo[128 * 64];

  const int tid = threadIdx.x;
  const int lane = tid & 63;
  const int wid = tid >> 6;
  const int wr = wid >> 1, wc = wid & 1;
  const int bn = blockIdx.x, bm = blockIdx.y;

  const int fr = lane & 15; // A row / B col / C col
  const int q8 = lane >> 4; // k-group (8 elems) / C row-group (4 rows)

  f32x4 acc[4][4];
#pragma unroll
  for (int i = 0; i < 4; ++i)
#pragma unroll
    for (int j = 0; j < 4; ++j) acc[i][j] = (f32x4){0.f, 0.f, 0.f, 0.f};

  const int o_base = wid * 1024 + lane * 16; // byte offset within 16KB tile (+ i*4096)
  const char* gA_hi = (const char*)mA_hi + (size_t)(bm * 128) * (D_DIM * 2);
  const char* gA_lo = (const char*)mA_lo + (size_t)(bm * 128) * (D_DIM * 2);
  const char* gB_hi = (const char*)cn_hi + (size_t)(bn * 128) * (D_DIM * 2);
  const char* gB_lo = (const char*)cn_lo + (size_t)(bn * 128) * (D_DIM * 2);

  for (int kt = 0; kt < D_DIM / 64; ++kt) {
    const int kbyte = kt * 128;
#pragma unroll
    for (int i = 0; i < 4; ++i) {
      const int o = o_base + i * 4096;
      const int row = o >> 7;     // 128 B per LDS row
      const int cbyt = o & 127;
      const size_t goff = (size_t)row * (D_DIM * 2) + kbyte + cbyt;
      const int loff = wid * 1024 + i * 4096;
      __builtin_amdgcn_global_load_lds((const __attribute__((address_space(1))) void*)(gA_hi + goff),
                                       (__attribute__((address_space(3))) void*)((char*)As_hi + loff), 16, 0, 0);
      __builtin_amdgcn_global_load_lds((const __attribute__((address_space(1))) void*)(gA_lo + goff),
                                       (__attribute__((address_space(3))) void*)((char*)As_lo + loff), 16, 0, 0);
      __builtin_amdgcn_global_load_lds((const __attribute__((address_space(1))) void*)(gB_hi + goff),
                                       (__attribute__((address_space(3))) void*)((char*)Bs_hi + loff), 16, 0, 0);
      __builtin_amdgcn_global_load_lds((const __attribute__((address_space(1))) void*)(gB_lo + goff),
                                       (__attribute__((address_space(3))) void*)((char*)Bs_lo + loff), 16, 0, 0);
    }
    __syncthreads();

#pragma unroll
    for (int kk = 0; kk < 2; ++kk) {
      bf16x8 ah[4], al[4], bh[4], bl[4];
      const int co = kk * 32 + q8 * 8;
#pragma unroll
      for (int mi = 0; mi < 4; ++mi) {
        const int r = wr * 64 + mi * 16 + fr;
        ah[mi] = *(const bf16x8*)&As_hi[r * 64 + co];
        al[mi] = *(const bf16x8*)&As_lo[r * 64 + co];
      }
#pragma unroll
      for (int ni = 0; ni < 4; ++ni) {
        const int r = wc * 64 + ni * 16 + fr;
        bh[ni] = *(const bf16x8*)&Bs_hi[r * 64 + co];
        bl[ni] = *(const bf16x8*)&Bs_lo[r * 64 + co];
      }
#pragma unroll
      for (int mi = 0; mi < 4; ++mi)
#pragma unroll
        for (int ni = 0; ni < 4; ++ni) {
          acc[mi][ni] = __builtin_amdgcn_mfma_f32_16x16x32_bf16(ah[mi], bh[ni], acc[mi][ni], 0, 0, 0);
          acc[mi][ni] = __builtin_amdgcn_mfma_f32_16x16x32_bf16(ah[mi], bl[ni], acc[mi][ni], 0, 0, 0);
          acc[mi][ni] = __builtin_amdgcn_mfma_f32_16x16x32_bf16(al[mi], bh[ni], acc[mi][ni], 0, 0, 0);
        }
    }
    __syncthreads();
  }

  // C layout (verified m89/m91): col = lane&15, row = (lane>>4)*4 + reg
  const int row_base = bm * 128 + wr * 64 + q8 * 4;
  const int col_base = bn * 128 + wc * 64 + fr;
#pragma unroll
  for (int mi = 0; mi < 4; ++mi)
#pragma unroll
    for (int ni = 0; ni < 4; ++ni) {
      const int r0 = row_base + mi * 16;
      const int c = col_base + ni * 16;
#pragma unroll
      for (int r = 0; r < 4; ++r)
        sim[(size_t)(r0 + r) * K_CB + c] = acc[mi][ni][r];
    }
}

// ---------------- epilogue: one WAVE per row; no barriers, no max-pass ----------------
// exp(l2) is safe un-shifted: gumbel(f32 bits) in [-4.48, 16.7], sim in [-1,1]
// => exp(l2) in [4e-3, 4.4e7]; softmax identical to max-subtracted form to ~ulp.
__global__ void __launch_bounds__(256) gumbel_epilogue(float* __restrict__ simw, // in: sim, out: weights_soft
                                                       float* __restrict__ zq,
                                                       float* __restrict__ idxf,
                                                       const float* __restrict__ cb,
                                                       u32 k1a, u32 k1b, u32 k2a, u32 k2b) {
  const int lane = threadIdx.x & 63, wid = threadIdx.x >> 6;
  const int n = blockIdx.x * 4 + wid;
  float4* row4 = (float4*)(simw + (size_t)n * K_CB);
  const u32 kbase = (u32)n * K_CB;

  float p2[16];
  float ps = 0.f;
  float bv = -1e30f; int bi = 0;
#pragma unroll
  for (int i = 0; i < 4; ++i) {
    const int f4i = lane + i * 64;      // float4 index in row
    const float4 s4 = row4[f4i];
#pragma unroll
    for (int j = 0; j < 4; ++j) {
      const u32 k = 4u * (u32)f4i + (u32)j;
      u32 a0, a1, b0, b1;
      tf2x32(k1a, k1b, 0u, kbase + k, a0, a1);
      tf2x32(k2a, k2b, 0u, kbase + k, b0, b1);
      const float s = (j == 0) ? s4.x : (j == 1) ? s4.y : (j == 2) ? s4.z : s4.w;
      const float l1 = s + gumbel_fast(a0 ^ a1);
      const float l2 = s + gumbel_fast(b0 ^ b1);
      const float p = __expf(l2);
      p2[i * 4 + j] = p;
      ps += p;
      if (l1 > bv) { bv = l1; bi = (int)k; }  // ascending k per thread -> first-max kept
    }
  }
  // wave reductions (argmax with first-index tie-break; sum)
#pragma unroll
  for (int off = 1; off < 64; off <<= 1) {
    const float ov = __shfl_xor(bv, off);
    const int oi = __shfl_xor(bi, off);
    if (ov > bv || (ov == bv && oi < bi)) { bv = ov; bi = oi; }
    ps += __shfl_xor(ps, off);
  }
  const float inv = 1.0f / ps;
#pragma unroll
  for (int i = 0; i < 4; ++i) {
    float4 o;
    o.x = p2[i * 4 + 0] * inv;
    o.y = p2[i * 4 + 1] * inv;
    o.z = p2[i * 4 + 2] * inv;
    o.w = p2[i * 4 + 3] * inv;
    row4[lane + i * 64] = o;
  }
  // z_q = codebook[argmax] (exact gather)
  const float4* crow = (const float4*)(cb + (size_t)bi * D_DIM);
  float4* zrow = (float4*)(zq + (size_t)n * D_DIM);
#pragma unroll
  for (int i = 0; i < 2; ++i) zrow[lane + i * 64] = crow[lane + i * 64];
  if (lane == 0) idxf[n] = (float)bi;
}

// ---------------- host ----------------
extern "C" void kernel_launch(void* const* d_in, const int* in_sizes, int n_in,
                              void* d_out, int out_size, void* d_ws, size_t ws_size,
                              hipStream_t stream) {
  const float* state = (const float*)d_in[0];
  const float* adv = (const float*)d_in[1];
  const float* cb = (const float*)d_in[2];

  char* ws = (char*)d_ws;
  u16* m_hi = (u16*)ws;                                 // 32 MB
  u16* m_lo = (u16*)(ws + (size_t)N_ROWS * D_DIM * 2);  // 32 MB
  u16* cn_hi = (u16*)(ws + (size_t)N_ROWS * D_DIM * 4);                            // 1 MB
  u16* cn_lo = (u16*)(ws + (size_t)N_ROWS * D_DIM * 4 + (size_t)K_CB * D_DIM * 2); // 1 MB

  float* zq = (float*)d_out;                       // [N, D]
  float* simw = zq + (size_t)N_ROWS * D_DIM;       // [N, K] sim -> weights_soft (in-place)
  float* idxf = simw + (size_t)N_ROWS * K_CB;      // [N, 1] as float

  // jax.random.key(42) -> (0,42); partitionable fold-like split: gk1=E(0,0), gk2=E(0,1)
  u32 gk1a, gk1b, gk2a, gk2b;
  tf2x32(0u, 42u, 0u, 0u, gk1a, gk1b);
  tf2x32(0u, 42u, 0u, 1u, gk2a, gk2b);

  hipLaunchKernelGGL(prep_codebook, dim3(K_CB / 4), dim3(256), 0, stream, cb, cn_hi, cn_lo);
  hipLaunchKernelGGL(prep_m, dim3(N_ROWS / 4), dim3(256), 0, stream, state, adv, m_hi, m_lo);
  hipLaunchKernelGGL(gemm_sim, dim3(K_CB / 128, N_ROWS / 128), dim3(256), 0, stream,
                     m_hi, m_lo, cn_hi, cn_lo, simw);
  hipLaunchKernelGGL(gumbel_epilogue, dim3(N_ROWS / 4), dim3(256), 0, stream,
                     simw, zq, idxf, cb, gk1a, gk1b, gk2a, gk2b);
}